// Round 2
// 621.998 us; speedup vs baseline: 1.0708x; 1.0708x over previous
//
#include <hip/hip_runtime.h>
#include <math.h>

// Problem constants
#define BATCH 16
#define G 5           // feature groups
#define CI 4          // in channels per group  (20/5)
#define CO 8          // out channels per group (40/5)
#define HW 384
#define KK 5          // padded kernel size (MAXK)
#define PADD 2

typedef float v2f __attribute__((ext_vector_type(2)));

// Weight layout in workspace: [G][CI][KY][KX][CO]  (CO contiguous) = 4000 floats
__global__ void gen_weights(const float* __restrict__ alphas,
                            const float* __restrict__ scales,
                            float* __restrict__ w) {
    int idx = blockIdx.x * blockDim.x + threadIdx.x;
    if (idx >= G * CI * KK * KK) return;   // 500
    int kx = idx % 5; int r = idx / 5;
    int ky = r % 5;   r /= 5;
    int i  = r % 4;   int s = r / 4;

    float mn = 0.2f * (float)s;
    float mx = mn + 0.2f;
    float sigma = 0.5f * (mx - mn) * tanhf(scales[s]) + 0.5f * (mn + mx);
    int fs = (s < 3) ? 1 : 2;          // static half filter sizes [1,1,1,2,2]
    int p  = 2 - fs;                   // zero-pad to 5x5

    float outw[CO];
    bool valid = (ky >= p) && (ky < 5 - p) && (kx >= p) && (kx < 5 - p);
    if (!valid) {
        #pragma unroll
        for (int o = 0; o < CO; ++o) outw[o] = 0.f;
    } else {
        float inv2s2 = 1.f / (2.f * sigma * sigma);
        float Gs = 0.f;
        for (int t = -fs; t <= fs; ++t) Gs += expf(-(float)(t * t) * inv2s2);
        const float sqrt2 = 1.41421356237309505f;
        float c = -1.f / (sigma * sqrt2);

        float xy = (float)(ky - p - fs);
        float xx = (float)(kx - p - fs);

        float gy = expf(-xy * xy * inv2s2) / Gs;
        float gx = expf(-xx * xx * inv2s2) / Gs;
        float uy = xy / (sigma * sqrt2);
        float ux = xx / (sigma * sqrt2);

        float dy[3], dx[3];
        dy[0] = gy;
        dy[1] = c * 2.f * uy * gy;
        dy[2] = c * c * (4.f * uy * uy - 2.f) * gy;
        dx[0] = gx;
        dx[1] = c * 2.f * ux * gx;
        dx[2] = c * c * (4.f * ux * ux - 2.f) * gx;

        float bas[6];
        bas[0] = dy[0] * dx[0];
        bas[1] = dy[0] * dx[1];
        bas[2] = dy[0] * dx[2];
        bas[3] = dy[1] * dx[0];
        bas[4] = dy[1] * dx[1];
        bas[5] = dy[2] * dx[0];

        #pragma unroll
        for (int o = 0; o < CO; ++o) {
            float acc = 0.f;
            #pragma unroll
            for (int n = 0; n < 6; ++n)
                acc += bas[n] * alphas[((s * 6 + n) * CI + i) * CO + o];
            outw[o] = acc;
        }
    }
    float* dst = w + ((((s * CI + i) * KK + ky) * KK + kx) * CO);
    #pragma unroll
    for (int o = 0; o < CO; ++o) dst[o] = outw[o];
}

// Tile: 32x32 outputs per block, 256 threads, each thread: 1y x 4x x 8o
#define TLE 32
#define IT 36          // input tile with halo: 32 + 2*2

__global__ __launch_bounds__(256) void conv_kernel(const float* __restrict__ in,
                                                   const float* __restrict__ w,
                                                   float* __restrict__ out) {
    __shared__ float s_in[CI][IT][IT];   // 20736 B

    const int tileX = blockIdx.x * TLE;
    const int tileY = blockIdx.y * TLE;
    const int bz = blockIdx.z;           // b*G + g
    const int g = bz % G;
    const int b = bz / G;
    const int tid = threadIdx.x;

    // stage input tile (with zero halo at borders)
    const float* inb = in + ((size_t)b * (G * CI) + g * CI) * (HW * HW);
    for (int l = tid; l < CI * IT * IT; l += 256) {
        int c = l / (IT * IT);
        int r = l - c * (IT * IT);
        int ly = r / IT;
        int lx = r - ly * IT;
        int gy = tileY - PADD + ly;
        int gx = tileX - PADD + lx;
        float v = 0.f;
        if ((unsigned)gy < (unsigned)HW && (unsigned)gx < (unsigned)HW)
            v = inb[c * (HW * HW) + gy * HW + gx];
        s_in[c][ly][lx] = v;
    }
    __syncthreads();

    const int xc = tid & 7;        // x-chunk 0..7
    const int ty = tid >> 3;       // output row 0..31
    const int xl0 = xc * 4;        // local x of first output

    // acc[op][x] : channel pair (2*op, 2*op+1) at output x
    v2f acc[4][4];
    #pragma unroll
    for (int op = 0; op < 4; ++op)
        #pragma unroll
        for (int x = 0; x < 4; ++x) acc[op][x] = (v2f)0.f;

    // weights: block-uniform address -> scalar loads, operands live in SGPRs
    const v2f* wg = (const v2f*)(w + (size_t)g * (CI * KK * KK * CO));

    for (int i = 0; i < CI; ++i) {
        #pragma unroll
        for (int ky = 0; ky < KK; ++ky) {
            const float* row = &s_in[i][ty + ky][xl0];
            float4 a0 = *(const float4*)(row);
            float4 a1 = *(const float4*)(row + 4);
            float iv[8] = {a0.x, a0.y, a0.z, a0.w, a1.x, a1.y, a1.z, a1.w};

            const v2f* wrow = wg + (size_t)(i * (KK * KK) + ky * KK) * 4;
            #pragma unroll
            for (int kx = 0; kx < KK; ++kx) {
                v2f W0 = wrow[kx * 4 + 0];
                v2f W1 = wrow[kx * 4 + 1];
                v2f W2 = wrow[kx * 4 + 2];
                v2f W3 = wrow[kx * 4 + 3];
                #pragma unroll
                for (int x = 0; x < 4; ++x) {
                    const int t = kx + x;        // compile-time after unroll
                    v2f pv = {iv[t], iv[t]};
                    acc[0][x] += W0 * pv;
                    acc[1][x] += W1 * pv;
                    acc[2][x] += W2 * pv;
                    acc[3][x] += W3 * pv;
                }
            }
        }
    }

    // write 8 output channels x 4 consecutive x as float4
    const int oy = tileY + ty;
    float* outb = out + (((size_t)b * (G * CO) + g * CO) * HW + oy) * HW + tileX + xl0;
    #pragma unroll
    for (int o = 0; o < CO; ++o) {
        float4 rr;
        rr.x = acc[o >> 1][0][o & 1];
        rr.y = acc[o >> 1][1][o & 1];
        rr.z = acc[o >> 1][2][o & 1];
        rr.w = acc[o >> 1][3][o & 1];
        *(float4*)(outb + (size_t)o * (HW * HW)) = rr;
    }
}

extern "C" void kernel_launch(void* const* d_in, const int* in_sizes, int n_in,
                              void* d_out, int out_size, void* d_ws, size_t ws_size,
                              hipStream_t stream) {
    const float* data   = (const float*)d_in[0];
    const float* alphas = (const float*)d_in[1];
    const float* scales = (const float*)d_in[2];
    float* out = (float*)d_out;
    float* w   = (float*)d_ws;   // 4000 floats = 16 KB

    gen_weights<<<2, 256, 0, stream>>>(alphas, scales, w);

    dim3 grid(HW / TLE, HW / TLE, BATCH * G);   // (12, 12, 80)
    conv_kernel<<<grid, 256, 0, stream>>>(data, w, out);
}

// Round 3
// 619.172 us; speedup vs baseline: 1.0757x; 1.0046x over previous
//
#include <hip/hip_runtime.h>
#include <math.h>

// Problem constants
#define BATCH 16
#define G 5           // feature groups
#define CI 4          // in channels per group  (20/5)
#define CO 8          // out channels per group (40/5)
#define HW 384
#define KK 5          // padded kernel size (MAXK)
#define PADD 2

typedef float v2f __attribute__((ext_vector_type(2)));
typedef unsigned long long u64;

// Weight layout in workspace: [G][CI][KY][KX][CO]  (CO contiguous) = 4000 floats
__global__ void gen_weights(const float* __restrict__ alphas,
                            const float* __restrict__ scales,
                            float* __restrict__ w) {
    int idx = blockIdx.x * blockDim.x + threadIdx.x;
    if (idx >= G * CI * KK * KK) return;   // 500
    int kx = idx % 5; int r = idx / 5;
    int ky = r % 5;   r /= 5;
    int i  = r % 4;   int s = r / 4;

    float mn = 0.2f * (float)s;
    float mx = mn + 0.2f;
    float sigma = 0.5f * (mx - mn) * tanhf(scales[s]) + 0.5f * (mn + mx);
    int fs = (s < 3) ? 1 : 2;          // static half filter sizes [1,1,1,2,2]
    int p  = 2 - fs;                   // zero-pad to 5x5

    float outw[CO];
    bool valid = (ky >= p) && (ky < 5 - p) && (kx >= p) && (kx < 5 - p);
    if (!valid) {
        #pragma unroll
        for (int o = 0; o < CO; ++o) outw[o] = 0.f;
    } else {
        float inv2s2 = 1.f / (2.f * sigma * sigma);
        float Gs = 0.f;
        for (int t = -fs; t <= fs; ++t) Gs += expf(-(float)(t * t) * inv2s2);
        const float sqrt2 = 1.41421356237309505f;
        float c = -1.f / (sigma * sqrt2);

        float xy = (float)(ky - p - fs);
        float xx = (float)(kx - p - fs);

        float gy = expf(-xy * xy * inv2s2) / Gs;
        float gx = expf(-xx * xx * inv2s2) / Gs;
        float uy = xy / (sigma * sqrt2);
        float ux = xx / (sigma * sqrt2);

        float dy[3], dx[3];
        dy[0] = gy;
        dy[1] = c * 2.f * uy * gy;
        dy[2] = c * c * (4.f * uy * uy - 2.f) * gy;
        dx[0] = gx;
        dx[1] = c * 2.f * ux * gx;
        dx[2] = c * c * (4.f * ux * ux - 2.f) * gx;

        float bas[6];
        bas[0] = dy[0] * dx[0];
        bas[1] = dy[0] * dx[1];
        bas[2] = dy[0] * dx[2];
        bas[3] = dy[1] * dx[0];
        bas[4] = dy[1] * dx[1];
        bas[5] = dy[2] * dx[0];

        #pragma unroll
        for (int o = 0; o < CO; ++o) {
            float acc = 0.f;
            #pragma unroll
            for (int n = 0; n < 6; ++n)
                acc += bas[n] * alphas[((s * 6 + n) * CI + i) * CO + o];
            outw[o] = acc;
        }
    }
    float* dst = w + ((((s * CI + i) * KK + ky) * KK + kx) * CO);
    #pragma unroll
    for (int o = 0; o < CO; ++o) dst[o] = outw[o];
}

// Tile: 32x32 outputs per block, 256 threads, each thread: 1y x 4x x 8o
#define TLE 32
#define IT 36          // input tile with halo: 32 + 2*2

// acc (f32 pair over channels 2o,2o+1) += W (sgpr channel pair) * broadcast(input)
// LO: broadcast low half of input pair p; HI: broadcast high half (via op_sel)
#define PKFMA_LO(a, W, p) \
    asm("v_pk_fma_f32 %0, %1, %2, %0 op_sel:[0,0,0] op_sel_hi:[1,0,1]" \
        : "+v"(a) : "s"(W), "v"(p))
#define PKFMA_HI(a, W, p) \
    asm("v_pk_fma_f32 %0, %1, %2, %0 op_sel:[0,1,0] op_sel_hi:[1,1,1]" \
        : "+v"(a) : "s"(W), "v"(p))

__global__ __launch_bounds__(256) void conv_kernel(const float* __restrict__ in,
                                                   const float* __restrict__ w,
                                                   float* __restrict__ out) {
    __shared__ float s_in[CI][IT][IT];   // 20736 B

    const int tileX = blockIdx.x * TLE;
    const int tileY = blockIdx.y * TLE;
    const int bz = blockIdx.z;           // b*G + g
    const int g = bz % G;
    const int b = bz / G;
    const int tid = threadIdx.x;

    // stage input tile (with zero halo at borders)
    const float* inb = in + ((size_t)b * (G * CI) + g * CI) * (HW * HW);
    for (int l = tid; l < CI * IT * IT; l += 256) {
        int c = l / (IT * IT);
        int r = l - c * (IT * IT);
        int ly = r / IT;
        int lx = r - ly * IT;
        int gy = tileY - PADD + ly;
        int gx = tileX - PADD + lx;
        float v = 0.f;
        if ((unsigned)gy < (unsigned)HW && (unsigned)gx < (unsigned)HW)
            v = inb[c * (HW * HW) + gy * HW + gx];
        s_in[c][ly][lx] = v;
    }
    __syncthreads();

    const int xc = tid & 7;        // x-chunk 0..7
    const int ty = tid >> 3;       // output row 0..31
    const int xl0 = xc * 4;        // local x of first output

    // acc[op][x] : channel pair (2*op, 2*op+1) at output x
    v2f acc[4][4];
    #pragma unroll
    for (int op = 0; op < 4; ++op)
        #pragma unroll
        for (int x = 0; x < 4; ++x) acc[op][x] = (v2f)0.f;

    // weights viewed as u64 channel-pairs, block-uniform address -> SGPR via s_load
    const u64* wg = (const u64*)(w + (size_t)g * (CI * KK * KK * CO));

    for (int i = 0; i < CI; ++i) {
        #pragma unroll
        for (int ky = 0; ky < KK; ++ky) {
            const float* row = &s_in[i][ty + ky][xl0];
            float4 a0 = *(const float4*)(row);
            float4 a1 = *(const float4*)(row + 4);
            v2f P[4];
            P[0][0] = a0.x; P[0][1] = a0.y;
            P[1][0] = a0.z; P[1][1] = a0.w;
            P[2][0] = a1.x; P[2][1] = a1.y;
            P[3][0] = a1.z; P[3][1] = a1.w;

            const u64* wrow = wg + (size_t)(i * (KK * KK) + ky * KK) * 4;
            #pragma unroll
            for (int kx = 0; kx < KK; ++kx) {
                u64 W0 = wrow[kx * 4 + 0];
                u64 W1 = wrow[kx * 4 + 1];
                u64 W2 = wrow[kx * 4 + 2];
                u64 W3 = wrow[kx * 4 + 3];
                #pragma unroll
                for (int x = 0; x < 4; ++x) {
                    const int t = kx + x;        // compile-time after unroll
                    if (t & 1) {
                        PKFMA_HI(acc[0][x], W0, P[t >> 1]);
                        PKFMA_HI(acc[1][x], W1, P[t >> 1]);
                        PKFMA_HI(acc[2][x], W2, P[t >> 1]);
                        PKFMA_HI(acc[3][x], W3, P[t >> 1]);
                    } else {
                        PKFMA_LO(acc[0][x], W0, P[t >> 1]);
                        PKFMA_LO(acc[1][x], W1, P[t >> 1]);
                        PKFMA_LO(acc[2][x], W2, P[t >> 1]);
                        PKFMA_LO(acc[3][x], W3, P[t >> 1]);
                    }
                }
            }
        }
    }

    // write 8 output channels x 4 consecutive x as float4
    const int oy = tileY + ty;
    float* outb = out + (((size_t)b * (G * CO) + g * CO) * HW + oy) * HW + tileX + xl0;
    #pragma unroll
    for (int o = 0; o < CO; ++o) {
        float4 rr;
        rr.x = acc[o >> 1][0][o & 1];
        rr.y = acc[o >> 1][1][o & 1];
        rr.z = acc[o >> 1][2][o & 1];
        rr.w = acc[o >> 1][3][o & 1];
        *(float4*)(outb + (size_t)o * (HW * HW)) = rr;
    }
}

extern "C" void kernel_launch(void* const* d_in, const int* in_sizes, int n_in,
                              void* d_out, int out_size, void* d_ws, size_t ws_size,
                              hipStream_t stream) {
    const float* data   = (const float*)d_in[0];
    const float* alphas = (const float*)d_in[1];
    const float* scales = (const float*)d_in[2];
    float* out = (float*)d_out;
    float* w   = (float*)d_ws;   // 4000 floats = 16 KB

    gen_weights<<<2, 256, 0, stream>>>(alphas, scales, w);

    dim3 grid(HW / TLE, HW / TLE, BATCH * G);   // (12, 12, 80)
    conv_kernel<<<grid, 256, 0, stream>>>(data, w, out);
}